// Round 5
// baseline (953.090 us; speedup 1.0000x reference)
//
#include <hip/hip_runtime.h>

// LSTM, T=2048 steps, B=2048, IN=5, H=10, fp32. Output [T*B, H].
// Round-4 theory: ~176 VALU instr/step/wave measured (891cy * 79% busy / 2
// waves / 2cy) vs ~65 coded => ~2.5x inflation from (a) register traffic
// (live set ~110 > VGPR_Count 76), (b) splat/addressing overhead. This round:
//   - x refill + out store use uniform SGPR base (SALU s_add per step) +
//     constant VGPR offset => per-step VALU address arithmetic eliminated.
//   - PF 8->4: ring 40->20 VGPRs (4-step lead ~1200cy still covers HBM miss).
//   - weights pinned via empty asm after prescale: no sinking/remat in-loop.
//   - store exec-mask removed: lanes 10..63 clamp to j=9 and compute h
//     bit-identically, so all 64 lanes store (dup lanes write same value to
//     same address -- benign).
// Structure retained: ONE batch per wave; h broadcast via v_readlane (SGPR
// dst, no LDS/lgkmcnt on chain); weights/biases pre-scaled into exp2 domain;
// cell state in scaled domain cs2 = -2*log2(e)*c; vector-path x ring with
// in-order vmcnt partial waits; refill-free peeled epilogue.

#define T_STEPS 2048
#define BATCH   2048
#define NIN     5
#define NH      10
#define PF      4

typedef float v2f __attribute__((ext_vector_type(2)));

__device__ __forceinline__ float hw_exp2(float v) { return __builtin_amdgcn_exp2f(v); }
__device__ __forceinline__ float hw_rcp(float v)  { return __builtin_amdgcn_rcpf(v); }
__device__ __forceinline__ float readlane_f(float v, int srclane) {
    return __builtin_bit_cast(float,
        __builtin_amdgcn_readlane(__builtin_bit_cast(int, v), srclane));
}
__device__ __forceinline__ v2f splat2(float v) { v2f r; r.x = v; r.y = v; return r; }

__global__ __launch_bounds__(64, 2) void lstm_fused_kernel(
    const float* __restrict__ x,   const float* __restrict__ hx0,
    const float* __restrict__ cx0, const float* __restrict__ Wih,
    const float* __restrict__ Whh, const float* __restrict__ bih,
    const float* __restrict__ bhh, float* __restrict__ out)
{
    const float L2E2  = 2.8853900817779268f;  //  2*log2(e)
    const float NL2E  = -1.4426950408889634f; // -log2(e)   (i,f,o scale)
    const float NL2E2 = -2.8853900817779268f; // -2*log2(e) (g scale, c domain)

    const int lane = threadIdx.x;
    int j = lane;                   // hidden unit 0..9; lanes 10..63 clamp to
    if (j > NH - 1) j = NH - 1;     // 9 and duplicate its (identical) compute

    const int b = blockIdx.x;       // ONE batch per wave

    // torch LSTMCell gate rows: i:[0,10) f:[10,20) g:[20,30) o:[30,40)
    const int ri = j, rf = NH + j, rg = 2 * NH + j, ro = 3 * NH + j;

    // Per-lane weights, packed (i,f) and (g,o), PRE-SCALED into exp2 domain.
    v2f wxif[NIN], wxgo[NIN], whif[NH], whgo[NH];
#pragma unroll
    for (int k = 0; k < NIN; ++k) {
        wxif[k].x = NL2E  * Wih[ri * NIN + k];  wxif[k].y = NL2E * Wih[rf * NIN + k];
        wxgo[k].x = NL2E2 * Wih[rg * NIN + k];  wxgo[k].y = NL2E * Wih[ro * NIN + k];
    }
#pragma unroll
    for (int k = 0; k < NH; ++k) {
        whif[k].x = NL2E  * Whh[ri * NH + k];   whif[k].y = NL2E * Whh[rf * NH + k];
        whgo[k].x = NL2E2 * Whh[rg * NH + k];   whgo[k].y = NL2E * Whh[ro * NH + k];
    }
    // Pin weights as opaque VGPR values: the compiler can no longer sink the
    // loads into the loop or rematerialize -- they must stay resident.
#pragma unroll
    for (int k = 0; k < NIN; ++k)
        asm volatile("" : "+v"(wxif[k]), "+v"(wxgo[k]));
#pragma unroll
    for (int k = 0; k < NH; ++k)
        asm volatile("" : "+v"(whif[k]), "+v"(whgo[k]));

    v2f bif, bgo;
    bif.x = NL2E  * (bih[ri] + bhh[ri]);  bif.y = NL2E * (bih[rf] + bhh[rf]);
    bgo.x = NL2E2 * (bih[rg] + bhh[rg]);  bgo.y = NL2E * (bih[ro] + bhh[ro]);

    // Full h vector (refreshed via v_readlane -> lands in SGPRs each step).
    float hv[NH];
#pragma unroll
    for (int k = 0; k < NH; ++k) hv[k] = hx0[b * NH + k];
    // Cell state in scaled domain: cs2 = -2*log2(e) * c  (lane-local).
    float cs2 = NL2E2 * cx0[b * NH + j];

    // One permanent zero VGPR as the vector offset: loads take the form
    //   global_load_dword v, v0, s[xs] offset:k*4
    // (uniform SGPR base advanced by SALU; no per-step VALU addressing).
    int vzero;
    asm volatile("v_mov_b32 %0, 0" : "=v"(vzero));

    const float* xs = x + (size_t)b * NIN;   // uniform -> SGPR pair
    float xr[PF][NIN];
#pragma unroll
    for (int q = 0; q < PF; ++q) {
#pragma unroll
        for (int k = 0; k < NIN; ++k)
            xr[q][k] = xs[vzero + k];
        xs += (size_t)BATCH * NIN;           // SALU advance
    }
    // xs now points at x[t=PF][b][0] -- the first refill target.

    float* outq = out + (size_t)b * NH;      // uniform -> SGPR pair

    // ---- one LSTM step (gates already in exp2 domain) ----
#define LSTM_STEP(QQ, DO_REFILL)                                              \
    {                                                                         \
        /* x-dot: independent of hv -> fills the readlane shadow */           \
        v2f aif0 = bif, ago0 = bgo;                                           \
        v2f aif1 = splat2(0.0f), ago1 = splat2(0.0f);                         \
        {                                                                     \
            v2f xx0 = splat2(xr[QQ][0]);                                      \
            v2f xx1 = splat2(xr[QQ][1]);                                      \
            v2f xx2 = splat2(xr[QQ][2]);                                      \
            v2f xx3 = splat2(xr[QQ][3]);                                      \
            v2f xx4 = splat2(xr[QQ][4]);                                      \
            aif0 += xx0 * wxif[0];  ago0 += xx0 * wxgo[0];                    \
            aif1 += xx1 * wxif[1];  ago1 += xx1 * wxgo[1];                    \
            aif0 += xx2 * wxif[2];  ago0 += xx2 * wxgo[2];                    \
            aif1 += xx3 * wxif[3];  ago1 += xx3 * wxgo[3];                    \
            aif0 += xx4 * wxif[4];  ago0 += xx4 * wxgo[4];                    \
        }                                                                     \
        if (DO_REFILL) {                                                      \
            _Pragma("unroll")                                                 \
            for (int k = 0; k < NIN; ++k)                                     \
                xr[QQ][k] = xs[vzero + k];   /* saddr + imm, no VALU */       \
            xs += (size_t)BATCH * NIN;       /* SALU advance */               \
        }                                                                     \
        /* h-dot: hv[k] are SGPRs from readlane (register deps, no waits) */  \
        _Pragma("unroll")                                                     \
        for (int k = 0; k < NH; k += 2) {                                     \
            v2f h0 = splat2(hv[k]);                                           \
            v2f h1 = splat2(hv[k + 1]);                                       \
            aif0 += h0 * whif[k];      ago0 += h0 * whgo[k];                  \
            aif1 += h1 * whif[k + 1];  ago1 += h1 * whgo[k + 1];              \
        }                                                                     \
        const v2f aif = aif0 + aif1;                                          \
        const v2f ago = ago0 + ago1;                                          \
        /* gates: accumulators are already exp2 arguments */                  \
        const float si  = hw_rcp(1.0f + hw_exp2(aif.x));                      \
        const float sf  = hw_rcp(1.0f + hw_exp2(aif.y));                      \
        const float rg_ = hw_rcp(1.0f + hw_exp2(ago.x));                      \
        const float so  = hw_rcp(1.0f + hw_exp2(ago.y));                      \
        const float tg2 = fmaf(-2.0f * L2E2, rg_, L2E2);  /* -2L2E*tanh(g) */ \
        cs2 = fmaf(sf, cs2, si * tg2);          /* scaled-domain c update */  \
        const float tc = fmaf(2.0f, hw_rcp(1.0f + hw_exp2(cs2)), -1.0f);      \
        const float h  = so * tc;                                             \
        /* all 64 lanes store: lanes 10..63 duplicate lane 9 (same value,     \
           same address) -> no exec-mask dance on the hot path */             \
        outq[j] = h;                                                          \
        outq += (size_t)BATCH * NH;          /* SALU advance */               \
        /* sole cross-lane op: wave-wide h broadcast via VALU readlane */     \
        _Pragma("unroll")                                                     \
        for (int k = 0; k < NH; ++k)                                          \
            hv[k] = readlane_f(h, k);                                         \
    }

#pragma unroll 1
    for (int t0 = 0; t0 < T_STEPS - PF; t0 += PF) {
        LSTM_STEP(0, 1)
        LSTM_STEP(1, 1)
        LSTM_STEP(2, 1)
        LSTM_STEP(3, 1)
    }
    // refill-free epilogue window (t = T_STEPS-PF .. T_STEPS-1)
    LSTM_STEP(0, 0)
    LSTM_STEP(1, 0)
    LSTM_STEP(2, 0)
    LSTM_STEP(3, 0)
#undef LSTM_STEP
}

extern "C" void kernel_launch(void* const* d_in, const int* in_sizes, int n_in,
                              void* d_out, int out_size, void* d_ws, size_t ws_size,
                              hipStream_t stream) {
    const float* x   = (const float*)d_in[0];
    const float* hx0 = (const float*)d_in[1];
    const float* cx0 = (const float*)d_in[2];
    const float* Wih = (const float*)d_in[3];
    const float* Whh = (const float*)d_in[4];
    const float* bih = (const float*)d_in[5];
    const float* bhh = (const float*)d_in[6];
    float* out = (float*)d_out;

    lstm_fused_kernel<<<BATCH, 64, 0, stream>>>(x, hx0, cx0, Wih, Whh, bih, bhh, out);
}

// Round 6
// 858.380 us; speedup vs baseline: 1.1103x; 1.1103x over previous
//
#include <hip/hip_runtime.h>

// LSTM, T=2048 steps, B=2048, IN=5, H=10, fp32. Output [T*B, H].
// Round-6 theory: SIMD-issue-bound. Measured: ~700 VALU-issue cy/step/SIMD
// shared by 2 waves/SIMD (~175 instr/wave/step incl. ~2.5x codegen inflation
// we could not remove at source level -- VGPR_Count pinned 72-76 across
// launch_bounds/pin experiments). Per-wave instruction count is lane-parallel
// invariant, so: pack TWO batches per wave (A in lanes 0-31, B in lanes
// 32-63) -> 1024 waves = 1 wave/SIMD -> issue contention halves at ~constant
// per-wave cost. Only new cost: h broadcast needs 2x v_readlane + v_cndmask
// merge per element (~+35 ops/step vs ~350 saved).
//
// Reverted (round-5 regression bundle): SGPR-base addressing, weight pins.
// Kept: dup-lane store (no exec dance), PF=4 ring, exp2-domain prescaled
// weights, scaled-domain cell state, readlane broadcast (no LDS on chain).

#define T_STEPS 2048
#define BATCH   2048
#define NIN     5
#define NH      10
#define PF      4

typedef float v2f __attribute__((ext_vector_type(2)));

__device__ __forceinline__ float hw_exp2(float v) { return __builtin_amdgcn_exp2f(v); }
__device__ __forceinline__ float hw_rcp(float v)  { return __builtin_amdgcn_rcpf(v); }
__device__ __forceinline__ float readlane_f(float v, int srclane) {
    return __builtin_bit_cast(float,
        __builtin_amdgcn_readlane(__builtin_bit_cast(int, v), srclane));
}
__device__ __forceinline__ v2f splat2(float v) { v2f r; r.x = v; r.y = v; return r; }

__global__ __launch_bounds__(64, 1) void lstm_fused_kernel(
    const float* __restrict__ x,   const float* __restrict__ hx0,
    const float* __restrict__ cx0, const float* __restrict__ Wih,
    const float* __restrict__ Whh, const float* __restrict__ bih,
    const float* __restrict__ bhh, float* __restrict__ out)
{
    const float L2E2  = 2.8853900817779268f;  //  2*log2(e)
    const float NL2E  = -1.4426950408889634f; // -log2(e)   (i,f,o scale)
    const float NL2E2 = -2.8853900817779268f; // -2*log2(e) (g scale, c domain)

    const int lane = threadIdx.x;
    const int half = lane >> 5;               // 0: batch A, 1: batch B
    int j = lane & 31;                        // unit 0..9; lanes 10..31 /
    if (j > NH - 1) j = NH - 1;               // 42..63 clamp (dup compute)
    const bool lo = (lane < 32);

    const int b = blockIdx.x * 2 + half;      // TWO batches per wave

    // torch LSTMCell gate rows: i:[0,10) f:[10,20) g:[20,30) o:[30,40)
    const int ri = j, rf = NH + j, rg = 2 * NH + j, ro = 3 * NH + j;

    // Per-lane weights, packed (i,f) and (g,o), PRE-SCALED into exp2 domain.
    v2f wxif[NIN], wxgo[NIN], whif[NH], whgo[NH];
#pragma unroll
    for (int k = 0; k < NIN; ++k) {
        wxif[k].x = NL2E  * Wih[ri * NIN + k];  wxif[k].y = NL2E * Wih[rf * NIN + k];
        wxgo[k].x = NL2E2 * Wih[rg * NIN + k];  wxgo[k].y = NL2E * Wih[ro * NIN + k];
    }
#pragma unroll
    for (int k = 0; k < NH; ++k) {
        whif[k].x = NL2E  * Whh[ri * NH + k];   whif[k].y = NL2E * Whh[rf * NH + k];
        whgo[k].x = NL2E2 * Whh[rg * NH + k];   whgo[k].y = NL2E * Whh[ro * NH + k];
    }
    v2f bif, bgo;
    bif.x = NL2E  * (bih[ri] + bhh[ri]);  bif.y = NL2E * (bih[rf] + bhh[rf]);
    bgo.x = NL2E2 * (bih[rg] + bhh[rg]);  bgo.y = NL2E * (bih[ro] + bhh[ro]);

    // Full h vector of THIS lane's batch (refreshed each step via
    // readlane x2 + cndmask merge). Lives in VGPRs (per-half values).
    float hv[NH];
#pragma unroll
    for (int k = 0; k < NH; ++k) hv[k] = hx0[b * NH + k];
    // Cell state in scaled domain: cs2 = -2*log2(e) * c  (lane-local).
    float cs2 = NL2E2 * cx0[b * NH + j];

    // Per-lane x base (halves point at different batch rows).
    const float* xb = x + (size_t)b * NIN;
    float xr[PF][NIN];
#pragma unroll
    for (int q = 0; q < PF; ++q)
#pragma unroll
        for (int k = 0; k < NIN; ++k)
            xr[q][k] = xb[q * (BATCH * NIN) + k];

    float* outp = out + (size_t)b * NH + j;

    // ---- one LSTM step (gates already in exp2 domain) ----
#define LSTM_STEP(QQ, TT, DO_REFILL)                                          \
    {                                                                         \
        /* x-dot: independent of hv */                                        \
        v2f aif0 = bif, ago0 = bgo;                                           \
        v2f aif1 = splat2(0.0f), ago1 = splat2(0.0f);                         \
        {                                                                     \
            v2f xx0 = splat2(xr[QQ][0]);                                      \
            v2f xx1 = splat2(xr[QQ][1]);                                      \
            v2f xx2 = splat2(xr[QQ][2]);                                      \
            v2f xx3 = splat2(xr[QQ][3]);                                      \
            v2f xx4 = splat2(xr[QQ][4]);                                      \
            aif0 += xx0 * wxif[0];  ago0 += xx0 * wxgo[0];                    \
            aif1 += xx1 * wxif[1];  ago1 += xx1 * wxgo[1];                    \
            aif0 += xx2 * wxif[2];  ago0 += xx2 * wxgo[2];                    \
            aif1 += xx3 * wxif[3];  ago1 += xx3 * wxgo[3];                    \
            aif0 += xx4 * wxif[4];  ago0 += xx4 * wxgo[4];                    \
        }                                                                     \
        if (DO_REFILL) {                                                      \
            const int tn = (TT) + PF;   /* int math: byte offset < 2^31 */    \
            _Pragma("unroll")                                                 \
            for (int k = 0; k < NIN; ++k)                                     \
                xr[QQ][k] = xb[tn * (BATCH * NIN) + k];                       \
        }                                                                     \
        /* h-dot: hv are per-half VGPR broadcasts (register deps only) */     \
        _Pragma("unroll")                                                     \
        for (int k = 0; k < NH; k += 2) {                                     \
            v2f h0 = splat2(hv[k]);                                           \
            v2f h1 = splat2(hv[k + 1]);                                       \
            aif0 += h0 * whif[k];      ago0 += h0 * whgo[k];                  \
            aif1 += h1 * whif[k + 1];  ago1 += h1 * whgo[k + 1];              \
        }                                                                     \
        const v2f aif = aif0 + aif1;                                          \
        const v2f ago = ago0 + ago1;                                          \
        /* gates: accumulators are already exp2 arguments */                  \
        const float si  = hw_rcp(1.0f + hw_exp2(aif.x));                      \
        const float sf  = hw_rcp(1.0f + hw_exp2(aif.y));                      \
        const float rg_ = hw_rcp(1.0f + hw_exp2(ago.x));                      \
        const float so  = hw_rcp(1.0f + hw_exp2(ago.y));                      \
        const float tg2 = fmaf(-2.0f * L2E2, rg_, L2E2);  /* -2L2E*tanh(g) */ \
        cs2 = fmaf(sf, cs2, si * tg2);          /* scaled-domain c update */  \
        const float tc = fmaf(2.0f, hw_rcp(1.0f + hw_exp2(cs2)), -1.0f);      \
        const float h  = so * tc;                                             \
        /* all 64 lanes store; clamped dup lanes write same value/addr */     \
        outp[(TT) * (BATCH * NH)] = h;                                        \
        /* broadcast h[0..9] per half: 2x readlane + cndmask merge */         \
        _Pragma("unroll")                                                     \
        for (int k = 0; k < NH; ++k) {                                        \
            const float hA = readlane_f(h, k);                                \
            const float hB = readlane_f(h, 32 + k);                           \
            hv[k] = lo ? hA : hB;                                             \
        }                                                                     \
    }

#pragma unroll 1
    for (int t0 = 0; t0 < T_STEPS - PF; t0 += PF) {
        LSTM_STEP(0, t0 + 0, 1)
        LSTM_STEP(1, t0 + 1, 1)
        LSTM_STEP(2, t0 + 2, 1)
        LSTM_STEP(3, t0 + 3, 1)
    }
    // refill-free epilogue window (t = T_STEPS-PF .. T_STEPS-1)
    {
        const int t0 = T_STEPS - PF;
        LSTM_STEP(0, t0 + 0, 0)
        LSTM_STEP(1, t0 + 1, 0)
        LSTM_STEP(2, t0 + 2, 0)
        LSTM_STEP(3, t0 + 3, 0)
    }
#undef LSTM_STEP
}

extern "C" void kernel_launch(void* const* d_in, const int* in_sizes, int n_in,
                              void* d_out, int out_size, void* d_ws, size_t ws_size,
                              hipStream_t stream) {
    const float* x   = (const float*)d_in[0];
    const float* hx0 = (const float*)d_in[1];
    const float* cx0 = (const float*)d_in[2];
    const float* Wih = (const float*)d_in[3];
    const float* Whh = (const float*)d_in[4];
    const float* bih = (const float*)d_in[5];
    const float* bhh = (const float*)d_in[6];
    float* out = (float*)d_out;

    lstm_fused_kernel<<<BATCH / 2, 64, 0, stream>>>(x, hx0, cx0, Wih, Whh, bih, bhh, out);
}

// Round 8
// 753.060 us; speedup vs baseline: 1.2656x; 1.1399x over previous
//
#include <hip/hip_runtime.h>

// LSTM, T=2048 steps, B=2048, IN=5, H=10, fp32. Output [T*B, H].
// Round-7/8 model (reconciles rounds 1+6): transcendentals are QUARTER-RATE
// (wave64 v_exp/v_rcp ~16 issue-cy vs 2 for VALU). Old layout (lane = unit,
// all 4 gates per lane) costs 10 trans (160 cy) + 60 fma (120 cy) per step.
//   round1: 2 waves x ~350 = 700 cy/step/SIMD  (measured 700) ✓
//   round6: 1 wave  x ~420 + exposed stalls    (measured 830) ✓
// New layout: lane = (gate,unit). group g=lane>>4 in {i,f,g,o}, unit
// j=lane&15 (clamp 9). Per lane: ONE 15-length gate dot (15 fma), ONE
// gate nonlinearity (1 exp2 + 1 rcp + 1 fma with per-lane (cA,cB) --
// sigmoid for i/f/o, scaled tanh for g, no divergence), gather the 4 gate
// values per unit with 4 ds_bpermute (wave64-wide -- proven by the 766us
// baseline whose groups straddled lane 32), redundant cell update in all
// groups, h broadcast via 10 v_readlane. 1 batch/wave -> 2048 waves =
// 2 waves/SIMD (stall hiding restored). Live set ~67 regs -> fits 72.
// Trans/step: 10 -> 4. FMA/step: 60 -> 15.
// (Round 7 never ran: GPU acquisition timeout — resubmitted verbatim.)

#define T_STEPS 2048
#define BATCH   2048
#define NIN     5
#define NH      10
#define PF      4

__device__ __forceinline__ float hw_exp2(float v) { return __builtin_amdgcn_exp2f(v); }
__device__ __forceinline__ float hw_rcp(float v)  { return __builtin_amdgcn_rcpf(v); }
__device__ __forceinline__ float readlane_f(float v, int srclane) {
    return __builtin_bit_cast(float,
        __builtin_amdgcn_readlane(__builtin_bit_cast(int, v), srclane));
}
__device__ __forceinline__ float bperm_f(int byteidx, float v) {
    return __builtin_bit_cast(float,
        __builtin_amdgcn_ds_bpermute(byteidx, __builtin_bit_cast(int, v)));
}

__global__ __launch_bounds__(64) void lstm_fused_kernel(
    const float* __restrict__ x,   const float* __restrict__ hx0,
    const float* __restrict__ cx0, const float* __restrict__ Wih,
    const float* __restrict__ Whh, const float* __restrict__ bih,
    const float* __restrict__ bhh, float* __restrict__ out)
{
    const float L2E2  = 2.8853900817779268f;  //  2*log2(e)
    const float NL2E  = -1.4426950408889634f; // -log2(e)   (i,f,o prescale)
    const float NL2E2 = -2.8853900817779268f; // -2*log2(e) (g prescale, c domain)

    const int lane = threadIdx.x;
    const int g    = lane >> 4;               // 0:i 1:f 2:g 3:o
    int j = lane & 15;                        // unit 0..9; 10..15 clamp to 9
    if (j > NH - 1) j = NH - 1;               // (dup compute, benign)

    const int b = blockIdx.x;                 // ONE batch per wave

    // This lane's weight row r = g*NH + j, prescaled into exp2 domain.
    const int r = g * NH + j;
    const float scale = (g == 2) ? NL2E2 : NL2E;

    float wx[NIN], wh[NH];
#pragma unroll
    for (int k = 0; k < NIN; ++k) wx[k] = scale * Wih[r * NIN + k];
#pragma unroll
    for (int k = 0; k < NH; ++k)  wh[k] = scale * Whh[r * NH + k];
    const float bb = scale * (bih[r] + bhh[r]);

    // Per-lane nonlinearity constants: v = cA*s + cB with s = rcp(1+exp2(a)).
    //   i/f/o lanes: v = s = sigmoid(z)
    //   g lanes:     v = -2*L2E2*s + L2E2 = -2log2(e)*tanh(g)  (scaled domain)
    const float cA = (g == 2) ? (-2.0f * L2E2) : 1.0f;
    const float cB = (g == 2) ? L2E2 : 0.0f;

    // Gather indices (byte = srclane*4): unit j's gates live in lanes
    // j, 16+j, 32+j, 48+j (canonical, not the clamped dups).
    const int idx_i = j * 4;
    const int idx_f = (16 + j) * 4;
    const int idx_g = (32 + j) * 4;
    const int idx_o = (48 + j) * 4;

    // Full h vector in every lane (refreshed via v_readlane each step).
    float hv[NH];
#pragma unroll
    for (int k = 0; k < NH; ++k) hv[k] = hx0[b * NH + k];
    // Cell state of THIS lane's unit, scaled domain cs2 = -2*log2(e)*c.
    float cs2 = NL2E2 * cx0[b * NH + j];

    // PF-deep x prefetch ring (all lanes load the same 5 floats; L1 bcast).
    const float* xb = x + (size_t)b * NIN;
    float xr[PF][NIN];
#pragma unroll
    for (int q = 0; q < PF; ++q)
#pragma unroll
        for (int k = 0; k < NIN; ++k)
            xr[q][k] = xb[q * (BATCH * NIN) + k];

    float* outp = out + (size_t)b * NH + j;

    // ---- one LSTM step ----
#define LSTM_STEP(QQ, TT, DO_REFILL)                                          \
    {                                                                         \
        /* gate dot (15 fma, 2 accumulators), x part first (hv-independent) */\
        float a0 = fmaf(wx[0], xr[QQ][0], bb);                                \
        float a1 = wx[1] * xr[QQ][1];                                         \
        a0 = fmaf(wx[2], xr[QQ][2], a0);                                      \
        a1 = fmaf(wx[3], xr[QQ][3], a1);                                      \
        a0 = fmaf(wx[4], xr[QQ][4], a0);                                      \
        if (DO_REFILL) {                                                      \
            const int tn = (TT) + PF;                                         \
            _Pragma("unroll")                                                 \
            for (int k = 0; k < NIN; ++k)                                     \
                xr[QQ][k] = xb[tn * (BATCH * NIN) + k];                       \
        }                                                                     \
        _Pragma("unroll")                                                     \
        for (int k = 0; k < NH; k += 2) {                                     \
            a0 = fmaf(wh[k],     hv[k],     a0);                              \
            a1 = fmaf(wh[k + 1], hv[k + 1], a1);                              \
        }                                                                     \
        const float a = a0 + a1;                                              \
        /* own-gate nonlinearity: 1 exp2 + 1 rcp + 1 fma (no divergence) */   \
        const float s = hw_rcp(1.0f + hw_exp2(a));                            \
        const float v = fmaf(cA, s, cB);                                      \
        /* gather this unit's four gates (wave64 ds_bpermute) */              \
        const float vi = bperm_f(idx_i, v);                                   \
        const float vf = bperm_f(idx_f, v);                                   \
        const float vg = bperm_f(idx_g, v);                                   \
        const float vo = bperm_f(idx_o, v);                                   \
        /* cell update in scaled domain (all 4 groups duplicate: benign) */   \
        cs2 = fmaf(vf, cs2, vi * vg);                                         \
        const float tc = fmaf(2.0f, hw_rcp(1.0f + hw_exp2(cs2)), -1.0f);      \
        const float h  = vo * tc;                                             \
        /* all 64 lanes store (dup lanes: same value, same address) */        \
        outp[(TT) * (BATCH * NH)] = h;                                        \
        /* h broadcast: unit k's h lives in lane k -> 10 readlanes */         \
        _Pragma("unroll")                                                     \
        for (int k = 0; k < NH; ++k)                                          \
            hv[k] = readlane_f(h, k);                                         \
    }

#pragma unroll 1
    for (int t0 = 0; t0 < T_STEPS - PF; t0 += PF) {
        LSTM_STEP(0, t0 + 0, 1)
        LSTM_STEP(1, t0 + 1, 1)
        LSTM_STEP(2, t0 + 2, 1)
        LSTM_STEP(3, t0 + 3, 1)
    }
    // refill-free epilogue window (t = T_STEPS-PF .. T_STEPS-1)
    {
        const int t0 = T_STEPS - PF;
        LSTM_STEP(0, t0 + 0, 0)
        LSTM_STEP(1, t0 + 1, 0)
        LSTM_STEP(2, t0 + 2, 0)
        LSTM_STEP(3, t0 + 3, 0)
    }
#undef LSTM_STEP
}

extern "C" void kernel_launch(void* const* d_in, const int* in_sizes, int n_in,
                              void* d_out, int out_size, void* d_ws, size_t ws_size,
                              hipStream_t stream) {
    const float* x   = (const float*)d_in[0];
    const float* hx0 = (const float*)d_in[1];
    const float* cx0 = (const float*)d_in[2];
    const float* Wih = (const float*)d_in[3];
    const float* Whh = (const float*)d_in[4];
    const float* bih = (const float*)d_in[5];
    const float* bhh = (const float*)d_in[6];
    float* out = (float*)d_out;

    lstm_fused_kernel<<<BATCH, 64, 0, stream>>>(x, hx0, cx0, Wih, Whh, bih, bhh, out);
}